// Round 15
// baseline (314.816 us; speedup 1.0000x reference)
//
#include <hip/hip_runtime.h>
#include <hip/hip_bf16.h>

// Problem constants (CrossEncoder): B=4, QT=1024, N=2048, E=512, H=8, Dh=64
#define B_  4
#define QT_ 1024
#define N_  2048
#define E_  512
#define H_  8
#define DH_ 64

typedef float  f32x4  __attribute__((ext_vector_type(4)));
typedef __bf16 bf16x8 __attribute__((ext_vector_type(8)));
typedef unsigned short u16;
typedef u16 u16x4 __attribute__((ext_vector_type(4)));

// round-to-nearest-even f32 -> bf16
static __device__ __forceinline__ u16 f2bf(float f) {
    unsigned u = __builtin_bit_cast(unsigned, f);
    return (u16)((u + 0x7fffu + ((u >> 16) & 1u)) >> 16);
}

static __device__ __forceinline__ bf16x8 ldbf8(const u16* p) {
    uint4 v = *reinterpret_cast<const uint4*>(p);
    return __builtin_bit_cast(bf16x8, v);
}

#define MFMA16(a, b, c) __builtin_amdgcn_mfma_f32_16x16x32_bf16((a), (b), (c), 0, 0, 0)

// async global->LDS, 16B per lane; LDS dest = uniform base + lane*16 (linear)
static __device__ __forceinline__ void g2lds16(const u16* g, u16* l) {
    __builtin_amdgcn_global_load_lds((__attribute__((address_space(1))) void*)(void*)g,
                                     (__attribute__((address_space(3))) void*)l, 16, 0, 0);
}

// -------------------- fused prep: cvt (6144 blk) + wt (256 blk) + rope (768 blk) --------
// Also zeroes the 128 attn completion counters (block 6400, stream-ordered before attn_pv).
__global__ __launch_bounds__(256) void prep_all(const float* __restrict__ q,
                                                const float* __restrict__ kv,
                                                const float* __restrict__ Wq,
                                                const float* __restrict__ Wk,
                                                const float* __restrict__ Wv,
                                                const float* __restrict__ Wo,
                                                const int* __restrict__ qpos,
                                                const int* __restrict__ kvpos,
                                                u16* __restrict__ qbf,
                                                u16* __restrict__ kvbf,
                                                u16* __restrict__ wt4,
                                                float2* __restrict__ tq,
                                                float2* __restrict__ tk,
                                                int* __restrict__ counters) {
    __shared__ float t[64][65];
    const int bid = blockIdx.x, tid = threadIdx.x;
    if (bid < 6144) {
        const int QN4 = B_ * QT_ * E_ / 4;  // 524288
        int i = bid * 256 + tid;
        const float4* s;
        ushort4* d;
        if (i < QN4) {
            s = reinterpret_cast<const float4*>(q) + i;
            d = reinterpret_cast<ushort4*>(qbf) + i;
        } else {
            int j = i - QN4;
            s = reinterpret_cast<const float4*>(kv) + j;
            d = reinterpret_cast<ushort4*>(kvbf) + j;
        }
        float4 v = *s;
        ushort4 o;
        o.x = f2bf(v.x); o.y = f2bf(v.y); o.z = f2bf(v.z); o.w = f2bf(v.w);
        *d = o;
    } else if (bid < 6400) {
        const int idx = bid - 6144;
        const int z = idx >> 6, rem = idx & 63, xb = rem & 7, yb = rem >> 3;
        const float* W = (z == 0) ? Wq : (z == 1) ? Wk : (z == 2) ? Wv : Wo;
        u16* dst = wt4 + (size_t)z * E_ * E_;
        const int k0 = xb * 64, n0 = yb * 64;
#pragma unroll
        for (int i = 0; i < 16; i++) {
            int ix = tid + i * 256, r = ix >> 6, c = ix & 63;
            t[r][c] = W[(k0 + r) * E_ + n0 + c];
        }
        __syncthreads();
#pragma unroll
        for (int i = 0; i < 16; i++) {
            int ix = tid + i * 256, r = ix >> 6, c = ix & 63;
            dst[(n0 + r) * E_ + k0 + c] = f2bf(t[c][r]);
        }
    } else {
        if (bid == 6400 && tid < 128) counters[tid] = 0;  // reset completion counters
        const int QROWS = B_ * QT_;  // 4096
        int i = (bid - 6400) * 256 + tid;  // 196608 total
        int k = i & 15, row = i >> 4;
        float fr = exp2f((float)k * -0.41524101186092028f);  // log2(10000)/32
        int p;
        float2* dst;
        if (row < QROWS) { p = qpos[row]; dst = tq + i; }
        else { p = kvpos[row - QROWS]; dst = tk + (i - QROWS * 16); }
        float sn, cs;
        sincosf((float)p * fr, &sn, &cs);
        *dst = make_float2(cs, sn);
    }
}

// -------------------- fused Q+K+V projection GEMM (BK=32: 32KB LDS, all 640 resident) ----
__global__ __launch_bounds__(256) void proj_qkv(const u16* __restrict__ qbf,
                                                const u16* __restrict__ kvbf,
                                                const u16* __restrict__ wt4,
                                                const float* __restrict__ bq,
                                                const float* __restrict__ bk,
                                                const float* __restrict__ bv,
                                                u16* __restrict__ qhh,
                                                u16* __restrict__ khh,
                                                u16* __restrict__ vt,
                                                const float2* __restrict__ tq,
                                                const float2* __restrict__ tk) {
    __shared__ __align__(16) u16 la[2][128 * 32];
    __shared__ __align__(16) u16 lb[2][128 * 32];

    const int id = blockIdx.x;
    const int sw = (id & 7) * 80 + (id >> 3);  // bijective XCD swizzle over 640
    const bool isQ = (sw < 128);
    int m0, n0;
    const u16 *X, *W;
    if (isQ) { m0 = (sw >> 2) * 128; n0 = (sw & 3) * 128; X = qbf; W = wt4; }
    else { const int s2 = sw - 128; m0 = (s2 >> 3) * 128; n0 = (s2 & 7) * 128; X = kvbf; W = wt4 + 512 * 512; }

    const int tid = threadIdx.x, w = tid >> 6, lane = tid & 63;
    const int lr = lane & 15, lg = lane >> 4;
    const int wml = (w >> 1) * 64, wnl = (w & 1) * 64;

    auto stage = [&](const u16* gsrc, u16* lbuf) {
#pragma unroll
        for (int i = 0; i < 2; i++) {
            const int r0 = w * 32 + i * 16;
            const int row = r0 + (lane >> 2);
            const u16* src = gsrc + row * E_ + (((lane & 3) ^ (row & 3)) * 8);
            g2lds16(src, lbuf + r0 * 32);
        }
    };

    f32x4 acc[4][4];
#pragma unroll
    for (int i = 0; i < 4; i++)
#pragma unroll
        for (int j = 0; j < 4; j++) acc[i][j] = f32x4{0.f, 0.f, 0.f, 0.f};

    stage(X + m0 * E_, la[0]);
    stage(W + n0 * E_, lb[0]);
    __syncthreads();
    int buf = 0;
    for (int kt = 0; kt < E_ / 32; kt++) {
        if (kt + 1 < E_ / 32) {
            stage(X + m0 * E_ + (kt + 1) * 32, la[buf ^ 1]);
            stage(W + n0 * E_ + (kt + 1) * 32, lb[buf ^ 1]);
        }
        bf16x8 a[4], bb[4];
#pragma unroll
        for (int mb = 0; mb < 4; mb++) {
            const int r = wml + mb * 16 + lr;
            a[mb] = ldbf8(la[buf] + r * 32 + ((lg ^ (r & 3)) * 8));
        }
#pragma unroll
        for (int nb = 0; nb < 4; nb++) {
            const int r = wnl + nb * 16 + lr;
            bb[nb] = ldbf8(lb[buf] + r * 32 + ((lg ^ (r & 3)) * 8));
        }
        __builtin_amdgcn_s_setprio(1);
#pragma unroll
        for (int mb = 0; mb < 4; mb++)
#pragma unroll
            for (int nb = 0; nb < 4; nb++)
                acc[mb][nb] = MFMA16(a[mb], bb[nb], acc[mb][nb]);
        __builtin_amdgcn_s_setprio(0);
        __syncthreads();
        buf ^= 1;
    }

    const bool isV = !isQ && (n0 >= 512);  // wg-uniform
#pragma unroll
    for (int mb = 0; mb < 4; mb++) {
#pragma unroll
        for (int nb = 0; nb < 4; nb++) {
            const int col = n0 + wnl + nb * 16 + lr;  // C col = lane&15
            const float bs = isQ ? bq[col] : (isV ? bv[col - 512] : bk[col]);
#pragma unroll
            for (int r = 0; r < 4; r++) {
                const int row = m0 + wml + mb * 16 + lg * 4 + r;  // C row = (lane>>4)*4+reg
                float v = acc[mb][nb][r] + bs;
                if (isV) {
                    const int cv = col - 512, d = cv & 63, h = cv >> 6;
                    const int b = row >> 11, n = row & 2047;
                    vt[(((b * H_ + h) * (N_ / 64) + (n >> 6)) * DH_ + d) * 64 + (n & 63)] = f2bf(v);
                } else {
                    const int d = col & 63, h = col >> 6;
                    float2 t = isQ ? tq[row * 16 + (d >> 2)] : tk[row * 16 + (d >> 2)];
                    float other = __shfl_xor(v, 1);  // pair mate: col^1 lives in lane^1
                    float y = (d & 1) ? (other * t.y + v * t.x) : (v * t.x - other * t.y);
                    if (isQ) {
                        y *= 0.125f;  // softmax scale folded into Q
                        const int b = row >> 10, tok = row & 1023;
                        qhh[((b * H_ + h) * QT_ + tok) * DH_ + d] = f2bf(y);
                    } else {
                        const int b = row >> 11, tok = row & 2047;
                        khh[((b * H_ + h) * N_ + tok) * DH_ + d] = f2bf(y);
                    }
                }
            }
        }
    }
}

// -------------------- attn pass A: partial row sums (8 waves x 32 q-rows) ----------------
__global__ __launch_bounds__(512) void attn_sums(const u16* __restrict__ qh,
                                                 const u16* __restrict__ kh,
                                                 const int* __restrict__ kv_mask,
                                                 float* __restrict__ sums4) {
    __shared__ __align__(16) u16 kbuf[2][64 * 64];

    const int id = blockIdx.x;
    const int sw = (id & 7) * 64 + (id >> 3);   // XCD k gets 4 consecutive bh
    const int bh = sw >> 4, qt = (sw >> 2) & 3, ns = sw & 3;
    const int b = bh >> 3;
    const int tid = threadIdx.x, w = tid >> 6, lane = tid & 63;
    const int lr = lane & 15, lg = lane >> 4;
    const int q0 = qt * 256 + w * 32;

    const u16* qbase = qh + (bh * QT_ + q0) * DH_;
    bf16x8 qf[2][2];
#pragma unroll
    for (int mq = 0; mq < 2; mq++) {
        qf[mq][0] = ldbf8(qbase + (mq * 16 + lr) * DH_ + lg * 8);       // Q pre-scaled
        qf[mq][1] = ldbf8(qbase + (mq * 16 + lr) * DH_ + 32 + lg * 8);
    }
    const u16* kbase = kh + (size_t)bh * (N_ * DH_) + ns * 512 * DH_;
    const int* mbase = kv_mask + b * N_ + ns * 512;

    auto stageK = [&](int t, u16* kb) {
        const int r0 = w * 8;
        const int row = r0 + (lane >> 3);
        const int gsw = ((lane & 7) ^ (row & 7)) * 8;
        g2lds16(kbase + (t * 64 + row) * 64 + gsw, kb + r0 * 64);
    };

    float lsum[2][4] = {{0.f, 0.f, 0.f, 0.f}, {0.f, 0.f, 0.f, 0.f}};
    stageK(0, kbuf[0]);
    __syncthreads();
    for (int t = 0; t < 8; t++) {
        const u16* kc = kbuf[t & 1];
        if (t < 7) stageK(t + 1, kbuf[(t + 1) & 1]);
#pragma unroll
        for (int n = 0; n < 4; n++) {
            const int krow = n * 16 + lr;
            const u16* kp = kc + krow * 64;
            bf16x8 k0 = ldbf8(kp + ((lg ^ (krow & 7)) * 8));
            bf16x8 k1 = ldbf8(kp + (((lg + 4) ^ (krow & 7)) * 8));
            f32x4 c0 = f32x4{0.f, 0.f, 0.f, 0.f};
            f32x4 c1 = f32x4{0.f, 0.f, 0.f, 0.f};
            __builtin_amdgcn_s_setprio(1);
            c0 = MFMA16(qf[0][0], k0, c0);
            c0 = MFMA16(qf[0][1], k1, c0);
            c1 = MFMA16(qf[1][0], k0, c1);
            c1 = MFMA16(qf[1][1], k1, c1);
            __builtin_amdgcn_s_setprio(0);
            const bool keep = (mbase[t * 64 + krow] != 0);
#pragma unroll
            for (int r = 0; r < 4; r++) {
                lsum[0][r] += keep ? __expf(c0[r]) : 0.f;
                lsum[1][r] += keep ? __expf(c1[r]) : 0.f;
            }
        }
        __syncthreads();
    }
#pragma unroll
    for (int mq = 0; mq < 2; mq++)
#pragma unroll
        for (int r = 0; r < 4; r++) {
            float s = lsum[mq][r];
            s += __shfl_xor(s, 1); s += __shfl_xor(s, 2);
            s += __shfl_xor(s, 4); s += __shfl_xor(s, 8);
            if (lr == 0)
                sums4[((size_t)bh * QT_ + q0 + mq * 16 + lg * 4 + r) * 4 + ns] = s;
        }
}

// -------------------- attn pass B: attn + partial PV + fused last-wg ctx reduce -----------
// grid 512 (XCD-swizzled): (bh, qt of 4, ns of 4); 8 waves x 32 q-rows (2 A-blocks).
// Epilogue: write pvpart slice, threadfence, atomicAdd counter[bh*4+qt]; the 4th
// arriver reduces all 4 ns slices for its 256 q-rows and writes ctx (threadFenceReduction
// pattern; device-scope atomics per G12/G16). Replaces the ctx_reduce kernel.
__global__ __launch_bounds__(512, 4) void attn_pv(const u16* __restrict__ qh,
                                                  const u16* __restrict__ kh,
                                                  const u16* __restrict__ vt,
                                                  const int* __restrict__ kv_mask,
                                                  const float* __restrict__ sums4,
                                                  float* __restrict__ attn_out,
                                                  float* __restrict__ pvpart,
                                                  int* __restrict__ counters,
                                                  u16* __restrict__ ctx) {
    __shared__ __align__(16) u16 kbuf[2][64 * 64];
    __shared__ __align__(16) u16 vbuf[2][64 * 64];
    __shared__ unsigned PW[8][32][32];  // per-wave packed bf16-pair P (32 q), granule-swz
    __shared__ int lastFlag;

    const int id = blockIdx.x;
    const int sw = (id & 7) * 64 + (id >> 3);   // XCD k gets 4 consecutive bh
    const int bh = sw >> 4, qt = (sw >> 2) & 3, ns = sw & 3;
    const int b = bh >> 3, h = bh & 7;
    const int tid = threadIdx.x, w = tid >> 6, lane = tid & 63;
    const int lr = lane & 15, lg = lane >> 4;
    const int q0 = qt * 256 + w * 32;

    const u16* qbase = qh + (bh * QT_ + q0) * DH_;
    bf16x8 qf[2][2];
#pragma unroll
    for (int mq = 0; mq < 2; mq++) {
        qf[mq][0] = ldbf8(qbase + (mq * 16 + lr) * DH_ + lg * 8);       // Q pre-scaled
        qf[mq][1] = ldbf8(qbase + (mq * 16 + lr) * DH_ + 32 + lg * 8);
    }
    const u16* kbase = kh + (size_t)bh * (N_ * DH_) + ns * 512 * DH_;
    const u16* vbase = vt + (size_t)bh * (N_ * DH_) + ns * 512 * DH_;  // [8 t][64 d][64]
    const int* mbase = kv_mask + b * N_ + ns * 512;

    // total row sums -> inv
    float inv[2][4];
#pragma unroll
    for (int mq = 0; mq < 2; mq++)
#pragma unroll
        for (int r = 0; r < 4; r++) {
            float4 s4 = *reinterpret_cast<const float4*>(
                sums4 + ((size_t)bh * QT_ + q0 + mq * 16 + lg * 4 + r) * 4);
            float tot = s4.x + s4.y + s4.z + s4.w;
            inv[mq][r] = (tot > 0.f) ? (1.0f / tot) : 0.f;  // all-masked -> attn = ctx = 0
        }

    // stage K tile [64 kv][64 d] + V tile [64 d][64 kv]: wave w stages rows [w*8, w*8+8)
    auto stage = [&](int t, u16* kb, u16* vb) {
        const int r0 = w * 8;
        const int row = r0 + (lane >> 3);
        const int gsw = ((lane & 7) ^ (row & 7)) * 8;
        g2lds16(kbase + (t * 64 + row) * 64 + gsw, kb + r0 * 64);
        g2lds16(vbase + (t * 64 + row) * 64 + gsw, vb + r0 * 64);
    };

    f32x4 pv[2][4];
#pragma unroll
    for (int mq = 0; mq < 2; mq++)
#pragma unroll
        for (int i = 0; i < 4; i++) pv[mq][i] = f32x4{0.f, 0.f, 0.f, 0.f};
    unsigned(*P)[32] = PW[w];
    float* abase = attn_out + ((size_t)(bh * QT_ + q0)) * N_ + ns * 512;
    const int srow = lane >> 4, cq = lane & 15;  // store: 4 rows x 256B per instr

    stage(0, kbuf[0], vbuf[0]);
    __syncthreads();
    for (int t = 0; t < 8; t++) {
        const u16* kc = kbuf[t & 1];
        const u16* vc = vbuf[t & 1];
        if (t < 7) stage(t + 1, kbuf[(t + 1) & 1], vbuf[(t + 1) & 1]);
#pragma unroll
        for (int n = 0; n < 4; n++) {
            const int krow = n * 16 + lr;
            const u16* kp = kc + krow * 64;
            bf16x8 k0 = ldbf8(kp + ((lg ^ (krow & 7)) * 8));
            bf16x8 k1 = ldbf8(kp + (((lg + 4) ^ (krow & 7)) * 8));
            f32x4 c0 = f32x4{0.f, 0.f, 0.f, 0.f};
            f32x4 c1 = f32x4{0.f, 0.f, 0.f, 0.f};
            __builtin_amdgcn_s_setprio(1);
            c0 = MFMA16(qf[0][0], k0, c0);
            c0 = MFMA16(qf[0][1], k1, c0);
            c1 = MFMA16(qf[1][0], k0, c1);
            c1 = MFMA16(qf[1][1], k1, c1);
            __builtin_amdgcn_s_setprio(0);
            const bool keep = (mbase[t * 64 + krow] != 0);
#pragma unroll
            for (int mq = 0; mq < 2; mq++) {
#pragma unroll
                for (int r = 0; r < 4; r++) {
                    float p = keep ? (__expf((mq ? c1 : c0)[r]) * inv[mq][r]) : 0.f;
                    float hi = __shfl_xor(p, 1);
                    __bf16 lo_b = (__bf16)p, hi_b = (__bf16)hi;
                    unsigned pk = ((unsigned)__builtin_bit_cast(u16, hi_b) << 16) |
                                  (unsigned)__builtin_bit_cast(u16, lo_b);
                    if (!(lr & 1)) {
                        const int row = mq * 16 + lg * 4 + r, c32 = n * 8 + (lr >> 1);
                        P[row][(((c32 >> 2) ^ (row & 7)) << 2) + (c32 & 3)] = pk;
                    }
                }
            }
        }
        // attn stores: read packed P (b64), unpack bf16->f32, 4 rows x 256B segments
#pragma unroll
        for (int i = 0; i < 8; i++) {
            const int row = i * 4 + srow, rw = row & 7;
            const int m = (((cq >> 1) ^ rw) << 2) + ((cq & 1) << 1);
            uint2 pp = *reinterpret_cast<const uint2*>(&P[row][m]);
            f32x4 vv;
            vv[0] = __builtin_bit_cast(float, pp.x << 16);
            vv[1] = __builtin_bit_cast(float, pp.x & 0xffff0000u);
            vv[2] = __builtin_bit_cast(float, pp.y << 16);
            vv[3] = __builtin_bit_cast(float, pp.y & 0xffff0000u);
            *reinterpret_cast<f32x4*>(abase + (size_t)row * N_ + t * 64 + cq * 4) = vv;
        }
        // PV: ctx[32q,64d] += P @ V-tile; V b128 frags loaded once, reused for both mq
#pragma unroll
        for (int ks = 0; ks < 2; ks++) {
            bf16x8 bv[4];
#pragma unroll
            for (int nb = 0; nb < 4; nb++) {
                const int vrow = nb * 16 + lr;
                bv[nb] = ldbf8(vc + vrow * 64 + (((ks * 4 + lg) ^ (vrow & 7)) * 8));
            }
            const int g = (4 * ks + lg) ^ (lr & 7);
#pragma unroll
            for (int mq = 0; mq < 2; mq++) {
                uint4 a4 = *reinterpret_cast<const uint4*>(&P[mq * 16 + lr][g << 2]);
                bf16x8 af = __builtin_bit_cast(bf16x8, a4);
                __builtin_amdgcn_s_setprio(1);
#pragma unroll
                for (int nb = 0; nb < 4; nb++)
                    pv[mq][nb] = MFMA16(af, bv[nb], pv[mq][nb]);
                __builtin_amdgcn_s_setprio(0);
            }
        }
        __syncthreads();
    }

    // partial ctx: pvpart[ns][bh][q][64]
    float* pbase = pvpart + (((size_t)ns * 32 + bh) * QT_) * DH_;
#pragma unroll
    for (int mq = 0; mq < 2; mq++)
#pragma unroll
        for (int nb = 0; nb < 4; nb++)
#pragma unroll
            for (int r = 0; r < 4; r++)
                pbase[(size_t)(q0 + mq * 16 + lg * 4 + r) * DH_ + nb * 16 + lr] = pv[mq][nb][r];

    // ---- last-arriving wg of this (bh,qt) group reduces 4 slices -> ctx ----
    __threadfence();
    if (tid == 0) {
        int prev = atomicAdd(&counters[bh * 4 + qt], 1);
        lastFlag = (prev == 3);
    }
    __syncthreads();
    if (lastFlag) {
        __threadfence();  // acquire: make other wgs' pvpart writes visible
        const size_t SL = (size_t)32 * QT_ * DH_;
        const float* pb = pvpart + ((size_t)bh * QT_ + qt * 256) * DH_;  // slice 0 base
#pragma unroll
        for (int it = 0; it < 8; it++) {
            const int e = (it * 512 + tid) * 4;  // elem in 256 rows x 64 d
            const int row = e >> 6, d = e & 63;
            const size_t pi = (size_t)row * DH_ + d;
            f32x4 s0 = *reinterpret_cast<const f32x4*>(pb + pi);
            f32x4 s1 = *reinterpret_cast<const f32x4*>(pb + SL + pi);
            f32x4 s2 = *reinterpret_cast<const f32x4*>(pb + 2 * SL + pi);
            f32x4 s3 = *reinterpret_cast<const f32x4*>(pb + 3 * SL + pi);
            u16x4 o;
#pragma unroll
            for (int j = 0; j < 4; j++) o[j] = f2bf((s0[j] + s1[j]) + (s2[j] + s3[j]));
            *reinterpret_cast<u16x4*>(
                &ctx[((b * QT_ + qt * 256 + row) * H_ + h) * DH_ + d]) = o;
        }
    }
}

// -------------------- O projection: 64x64 tiles, grid 512 --------------------
__global__ __launch_bounds__(256) void proj_o(const u16* __restrict__ X,
                                              const u16* __restrict__ Wt,
                                              const float* __restrict__ bias,
                                              float* __restrict__ outp,
                                              const int* __restrict__ qmask) {
    __shared__ __align__(16) u16 la[2][64 * 64];
    __shared__ __align__(16) u16 lb[2][64 * 64];

    const int id = blockIdx.x;             // 512 blocks
    const int sw = (id & 7) * 64 + (id >> 3);
    const int m0 = (sw >> 3) * 64, n0 = (sw & 7) * 64;

    const int tid = threadIdx.x, w = tid >> 6, lane = tid & 63;
    const int lr = lane & 15, lg = lane >> 4;
    const int wml = (w >> 1) * 32, wnl = (w & 1) * 32;

    auto stage = [&](const u16* gsrc, u16* lbuf) {
#pragma unroll
        for (int i = 0; i < 2; i++) {
            const int r0 = w * 16 + i * 8;
            const int row = r0 + (lane >> 3);
            const u16* src = gsrc + row * E_ + (((lane & 7) ^ (row & 7)) * 8);
            g2lds16(src, lbuf + r0 * 64);
        }
    };

    f32x4 acc[2][2];
#pragma unroll
    for (int i = 0; i < 2; i++)
#pragma unroll
        for (int j = 0; j < 2; j++) acc[i][j] = f32x4{0.f, 0.f, 0.f, 0.f};

    stage(X + m0 * E_, la[0]);
    stage(Wt + n0 * E_, lb[0]);
    __syncthreads();
    int buf = 0;
    for (int kt = 0; kt < E_ / 64; kt++) {
        if (kt + 1 < E_ / 64) {
            stage(X + m0 * E_ + (kt + 1) * 64, la[buf ^ 1]);
            stage(Wt + n0 * E_ + (kt + 1) * 64, lb[buf ^ 1]);
        }
#pragma unroll
        for (int ks = 0; ks < 2; ks++) {
            bf16x8 a[2], bb[2];
#pragma unroll
            for (int mb = 0; mb < 2; mb++) {
                const int r = wml + mb * 16 + lr;
                a[mb] = ldbf8(la[buf] + r * 64 + (((ks * 4 + lg) ^ (r & 7)) * 8));
            }
#pragma unroll
            for (int nb = 0; nb < 2; nb++) {
                const int r = wnl + nb * 16 + lr;
                bb[nb] = ldbf8(lb[buf] + r * 64 + (((ks * 4 + lg) ^ (r & 7)) * 8));
            }
            __builtin_amdgcn_s_setprio(1);
#pragma unroll
            for (int mb = 0; mb < 2; mb++)
#pragma unroll
                for (int nb = 0; nb < 2; nb++)
                    acc[mb][nb] = MFMA16(a[mb], bb[nb], acc[mb][nb]);
            __builtin_amdgcn_s_setprio(0);
        }
        __syncthreads();
        buf ^= 1;
    }

#pragma unroll
    for (int mb = 0; mb < 2; mb++) {
#pragma unroll
        for (int nb = 0; nb < 2; nb++) {
            const int col = n0 + wnl + nb * 16 + lr;
            const float bs = bias[col];
#pragma unroll
            for (int r = 0; r < 4; r++) {
                const int row = m0 + wml + mb * 16 + lg * 4 + r;
                float v = acc[mb][nb][r] + bs;
                float m = (qmask[row] != 0) ? 1.0f : 0.0f;
                outp[row * E_ + col] = v * m;
            }
        }
    }
}

// -------------------- host launch --------------------
extern "C" void kernel_launch(void* const* d_in, const int* in_sizes, int n_in,
                              void* d_out, int out_size, void* d_ws, size_t ws_size,
                              hipStream_t stream) {
    (void)in_sizes; (void)n_in; (void)out_size; (void)ws_size;
    const float* q   = (const float*)d_in[0];
    const float* kv  = (const float*)d_in[1];
    const int* q_mask  = (const int*)d_in[2];
    const int* kv_mask = (const int*)d_in[3];
    const int* q_pos   = (const int*)d_in[4];
    const int* kv_pos  = (const int*)d_in[5];
    const float* Wq = (const float*)d_in[6];  const float* bq = (const float*)d_in[7];
    const float* Wk = (const float*)d_in[8];  const float* bk = (const float*)d_in[9];
    const float* Wv = (const float*)d_in[10]; const float* bv = (const float*)d_in[11];
    const float* Wo = (const float*)d_in[12]; const float* bo = (const float*)d_in[13];
    float* outp = (float*)d_out;

    char* ws = (char*)d_ws;
    size_t off = 0;
    auto carve = [&](size_t bytes) -> void* {
        void* p = ws + off;
        off = (off + bytes + 255) & ~(size_t)255;
        return p;
    };
    u16* qbf    = (u16*)carve((size_t)B_ * QT_ * E_ * 2);
    u16* kvbf   = (u16*)carve((size_t)B_ * N_ * E_ * 2);
    u16* wt4    = (u16*)carve((size_t)4 * E_ * E_ * 2);  // [Wq^T|Wk^T|Wv^T|Wo^T]
    u16* qhh    = (u16*)carve((size_t)B_ * H_ * QT_ * DH_ * 2);
    u16* khh    = (u16*)carve((size_t)B_ * H_ * N_ * DH_ * 2);
    u16* vt     = (u16*)carve((size_t)B_ * H_ * DH_ * N_ * 2);  // tiled [bh][32][64][64]
    u16* ctx    = (u16*)carve((size_t)B_ * QT_ * E_ * 2);
    float2* tq  = (float2*)carve((size_t)B_ * QT_ * 16 * sizeof(float2));
    float2* tk  = (float2*)carve((size_t)B_ * N_ * 16 * sizeof(float2));
    float* sums4  = (float*)carve((size_t)B_ * H_ * QT_ * 4 * sizeof(float));
    float* pvpart = (float*)carve((size_t)4 * B_ * H_ * QT_ * DH_ * sizeof(float));
    int* counters = (int*)carve(128 * sizeof(int));

    prep_all<<<7168, 256, 0, stream>>>(q, kv, Wq, Wk, Wv, Wo, q_pos, kv_pos,
                                       qbf, kvbf, wt4, tq, tk, counters);

    proj_qkv<<<640, 256, 0, stream>>>(qbf, kvbf, wt4, bq, bk, bv, qhh, khh, vt, tq, tk);

    attn_sums<<<512, 512, 0, stream>>>(qhh, khh, kv_mask, sums4);
    attn_pv<<<512, 512, 0, stream>>>(qhh, khh, vt, kv_mask, sums4,
                                     outp + (size_t)B_ * QT_ * E_, pvpart, counters, ctx);

    proj_o<<<512, 256, 0, stream>>>(ctx, wt4 + 3 * 512 * 512, bo, outp, q_mask);
}

// Round 16
// 147.670 us; speedup vs baseline: 2.1319x; 2.1319x over previous
//
#include <hip/hip_runtime.h>
#include <hip/hip_bf16.h>

// Problem constants (CrossEncoder): B=4, QT=1024, N=2048, E=512, H=8, Dh=64
#define B_  4
#define QT_ 1024
#define N_  2048
#define E_  512
#define H_  8
#define DH_ 64

typedef float  f32x4  __attribute__((ext_vector_type(4)));
typedef __bf16 bf16x8 __attribute__((ext_vector_type(8)));
typedef unsigned short u16;
typedef u16 u16x4 __attribute__((ext_vector_type(4)));

// round-to-nearest-even f32 -> bf16
static __device__ __forceinline__ u16 f2bf(float f) {
    unsigned u = __builtin_bit_cast(unsigned, f);
    return (u16)((u + 0x7fffu + ((u >> 16) & 1u)) >> 16);
}

static __device__ __forceinline__ bf16x8 ldbf8(const u16* p) {
    uint4 v = *reinterpret_cast<const uint4*>(p);
    return __builtin_bit_cast(bf16x8, v);
}

#define MFMA16(a, b, c) __builtin_amdgcn_mfma_f32_16x16x32_bf16((a), (b), (c), 0, 0, 0)

// async global->LDS, 16B per lane; LDS dest = uniform base + lane*16 (linear)
static __device__ __forceinline__ void g2lds16(const u16* g, u16* l) {
    __builtin_amdgcn_global_load_lds((__attribute__((address_space(1))) void*)(void*)g,
                                     (__attribute__((address_space(3))) void*)l, 16, 0, 0);
}

// -------------------- fused prep: cvt (6144 blk) + wt (256 blk) + rope (768 blk) --------
__global__ __launch_bounds__(256) void prep_all(const float* __restrict__ q,
                                                const float* __restrict__ kv,
                                                const float* __restrict__ Wq,
                                                const float* __restrict__ Wk,
                                                const float* __restrict__ Wv,
                                                const float* __restrict__ Wo,
                                                const int* __restrict__ qpos,
                                                const int* __restrict__ kvpos,
                                                u16* __restrict__ qbf,
                                                u16* __restrict__ kvbf,
                                                u16* __restrict__ wt4,
                                                float2* __restrict__ tq,
                                                float2* __restrict__ tk) {
    __shared__ float t[64][65];
    const int bid = blockIdx.x, tid = threadIdx.x;
    if (bid < 6144) {
        const int QN4 = B_ * QT_ * E_ / 4;  // 524288
        int i = bid * 256 + tid;
        const float4* s;
        ushort4* d;
        if (i < QN4) {
            s = reinterpret_cast<const float4*>(q) + i;
            d = reinterpret_cast<ushort4*>(qbf) + i;
        } else {
            int j = i - QN4;
            s = reinterpret_cast<const float4*>(kv) + j;
            d = reinterpret_cast<ushort4*>(kvbf) + j;
        }
        float4 v = *s;
        ushort4 o;
        o.x = f2bf(v.x); o.y = f2bf(v.y); o.z = f2bf(v.z); o.w = f2bf(v.w);
        *d = o;
    } else if (bid < 6400) {
        const int idx = bid - 6144;
        const int z = idx >> 6, rem = idx & 63, xb = rem & 7, yb = rem >> 3;
        const float* W = (z == 0) ? Wq : (z == 1) ? Wk : (z == 2) ? Wv : Wo;
        u16* dst = wt4 + (size_t)z * E_ * E_;
        const int k0 = xb * 64, n0 = yb * 64;
#pragma unroll
        for (int i = 0; i < 16; i++) {
            int ix = tid + i * 256, r = ix >> 6, c = ix & 63;
            t[r][c] = W[(k0 + r) * E_ + n0 + c];
        }
        __syncthreads();
#pragma unroll
        for (int i = 0; i < 16; i++) {
            int ix = tid + i * 256, r = ix >> 6, c = ix & 63;
            dst[(n0 + r) * E_ + k0 + c] = f2bf(t[c][r]);
        }
    } else {
        const int QROWS = B_ * QT_;  // 4096
        int i = (bid - 6400) * 256 + tid;  // 196608 total
        int k = i & 15, row = i >> 4;
        float fr = exp2f((float)k * -0.41524101186092028f);  // log2(10000)/32
        int p;
        float2* dst;
        if (row < QROWS) { p = qpos[row]; dst = tq + i; }
        else { p = kvpos[row - QROWS]; dst = tk + (i - QROWS * 16); }
        float sn, cs;
        sincosf((float)p * fr, &sn, &cs);
        *dst = make_float2(cs, sn);
    }
}

// -------------------- fused Q+K+V projection GEMM (BK=32: 32KB LDS, all 640 resident) ----
__global__ __launch_bounds__(256) void proj_qkv(const u16* __restrict__ qbf,
                                                const u16* __restrict__ kvbf,
                                                const u16* __restrict__ wt4,
                                                const float* __restrict__ bq,
                                                const float* __restrict__ bk,
                                                const float* __restrict__ bv,
                                                u16* __restrict__ qhh,
                                                u16* __restrict__ khh,
                                                u16* __restrict__ vt,
                                                const float2* __restrict__ tq,
                                                const float2* __restrict__ tk) {
    __shared__ __align__(16) u16 la[2][128 * 32];
    __shared__ __align__(16) u16 lb[2][128 * 32];

    const int id = blockIdx.x;
    const int sw = (id & 7) * 80 + (id >> 3);  // bijective XCD swizzle over 640
    const bool isQ = (sw < 128);
    int m0, n0;
    const u16 *X, *W;
    if (isQ) { m0 = (sw >> 2) * 128; n0 = (sw & 3) * 128; X = qbf; W = wt4; }
    else { const int s2 = sw - 128; m0 = (s2 >> 3) * 128; n0 = (s2 & 7) * 128; X = kvbf; W = wt4 + 512 * 512; }

    const int tid = threadIdx.x, w = tid >> 6, lane = tid & 63;
    const int lr = lane & 15, lg = lane >> 4;
    const int wml = (w >> 1) * 64, wnl = (w & 1) * 64;

    auto stage = [&](const u16* gsrc, u16* lbuf) {
#pragma unroll
        for (int i = 0; i < 2; i++) {
            const int r0 = w * 32 + i * 16;
            const int row = r0 + (lane >> 2);
            const u16* src = gsrc + row * E_ + (((lane & 3) ^ (row & 3)) * 8);
            g2lds16(src, lbuf + r0 * 32);
        }
    };

    f32x4 acc[4][4];
#pragma unroll
    for (int i = 0; i < 4; i++)
#pragma unroll
        for (int j = 0; j < 4; j++) acc[i][j] = f32x4{0.f, 0.f, 0.f, 0.f};

    stage(X + m0 * E_, la[0]);
    stage(W + n0 * E_, lb[0]);
    __syncthreads();
    int buf = 0;
    for (int kt = 0; kt < E_ / 32; kt++) {
        if (kt + 1 < E_ / 32) {
            stage(X + m0 * E_ + (kt + 1) * 32, la[buf ^ 1]);
            stage(W + n0 * E_ + (kt + 1) * 32, lb[buf ^ 1]);
        }
        bf16x8 a[4], bb[4];
#pragma unroll
        for (int mb = 0; mb < 4; mb++) {
            const int r = wml + mb * 16 + lr;
            a[mb] = ldbf8(la[buf] + r * 32 + ((lg ^ (r & 3)) * 8));
        }
#pragma unroll
        for (int nb = 0; nb < 4; nb++) {
            const int r = wnl + nb * 16 + lr;
            bb[nb] = ldbf8(lb[buf] + r * 32 + ((lg ^ (r & 3)) * 8));
        }
        __builtin_amdgcn_s_setprio(1);
#pragma unroll
        for (int mb = 0; mb < 4; mb++)
#pragma unroll
            for (int nb = 0; nb < 4; nb++)
                acc[mb][nb] = MFMA16(a[mb], bb[nb], acc[mb][nb]);
        __builtin_amdgcn_s_setprio(0);
        __syncthreads();
        buf ^= 1;
    }

    const bool isV = !isQ && (n0 >= 512);  // wg-uniform
#pragma unroll
    for (int mb = 0; mb < 4; mb++) {
#pragma unroll
        for (int nb = 0; nb < 4; nb++) {
            const int col = n0 + wnl + nb * 16 + lr;  // C col = lane&15
            const float bs = isQ ? bq[col] : (isV ? bv[col - 512] : bk[col]);
#pragma unroll
            for (int r = 0; r < 4; r++) {
                const int row = m0 + wml + mb * 16 + lg * 4 + r;  // C row = (lane>>4)*4+reg
                float v = acc[mb][nb][r] + bs;
                if (isV) {
                    const int cv = col - 512, d = cv & 63, h = cv >> 6;
                    const int b = row >> 11, n = row & 2047;
                    vt[(((b * H_ + h) * (N_ / 64) + (n >> 6)) * DH_ + d) * 64 + (n & 63)] = f2bf(v);
                } else {
                    const int d = col & 63, h = col >> 6;
                    float2 t = isQ ? tq[row * 16 + (d >> 2)] : tk[row * 16 + (d >> 2)];
                    float other = __shfl_xor(v, 1);  // pair mate: col^1 lives in lane^1
                    float y = (d & 1) ? (other * t.y + v * t.x) : (v * t.x - other * t.y);
                    if (isQ) {
                        y *= 0.125f;  // softmax scale folded into Q
                        const int b = row >> 10, tok = row & 1023;
                        qhh[((b * H_ + h) * QT_ + tok) * DH_ + d] = f2bf(y);
                    } else {
                        const int b = row >> 11, tok = row & 2047;
                        khh[((b * H_ + h) * N_ + tok) * DH_ + d] = f2bf(y);
                    }
                }
            }
        }
    }
}

// -------------------- attn pass A: partial row sums (8 waves x 32 q-rows) ----------------
__global__ __launch_bounds__(512) void attn_sums(const u16* __restrict__ qh,
                                                 const u16* __restrict__ kh,
                                                 const int* __restrict__ kv_mask,
                                                 float* __restrict__ sums4) {
    __shared__ __align__(16) u16 kbuf[2][64 * 64];

    const int id = blockIdx.x;
    const int sw = (id & 7) * 64 + (id >> 3);   // XCD k gets 4 consecutive bh
    const int bh = sw >> 4, qt = (sw >> 2) & 3, ns = sw & 3;
    const int b = bh >> 3;
    const int tid = threadIdx.x, w = tid >> 6, lane = tid & 63;
    const int lr = lane & 15, lg = lane >> 4;
    const int q0 = qt * 256 + w * 32;

    const u16* qbase = qh + (bh * QT_ + q0) * DH_;
    bf16x8 qf[2][2];
#pragma unroll
    for (int mq = 0; mq < 2; mq++) {
        qf[mq][0] = ldbf8(qbase + (mq * 16 + lr) * DH_ + lg * 8);       // Q pre-scaled
        qf[mq][1] = ldbf8(qbase + (mq * 16 + lr) * DH_ + 32 + lg * 8);
    }
    const u16* kbase = kh + (size_t)bh * (N_ * DH_) + ns * 512 * DH_;
    const int* mbase = kv_mask + b * N_ + ns * 512;

    auto stageK = [&](int t, u16* kb) {
        const int r0 = w * 8;
        const int row = r0 + (lane >> 3);
        const int gsw = ((lane & 7) ^ (row & 7)) * 8;
        g2lds16(kbase + (t * 64 + row) * 64 + gsw, kb + r0 * 64);
    };

    float lsum[2][4] = {{0.f, 0.f, 0.f, 0.f}, {0.f, 0.f, 0.f, 0.f}};
    stageK(0, kbuf[0]);
    __syncthreads();
    for (int t = 0; t < 8; t++) {
        const u16* kc = kbuf[t & 1];
        if (t < 7) stageK(t + 1, kbuf[(t + 1) & 1]);
#pragma unroll
        for (int n = 0; n < 4; n++) {
            const int krow = n * 16 + lr;
            const u16* kp = kc + krow * 64;
            bf16x8 k0 = ldbf8(kp + ((lg ^ (krow & 7)) * 8));
            bf16x8 k1 = ldbf8(kp + (((lg + 4) ^ (krow & 7)) * 8));
            f32x4 c0 = f32x4{0.f, 0.f, 0.f, 0.f};
            f32x4 c1 = f32x4{0.f, 0.f, 0.f, 0.f};
            __builtin_amdgcn_s_setprio(1);
            c0 = MFMA16(qf[0][0], k0, c0);
            c0 = MFMA16(qf[0][1], k1, c0);
            c1 = MFMA16(qf[1][0], k0, c1);
            c1 = MFMA16(qf[1][1], k1, c1);
            __builtin_amdgcn_s_setprio(0);
            const bool keep = (mbase[t * 64 + krow] != 0);
#pragma unroll
            for (int r = 0; r < 4; r++) {
                lsum[0][r] += keep ? __expf(c0[r]) : 0.f;
                lsum[1][r] += keep ? __expf(c1[r]) : 0.f;
            }
        }
        __syncthreads();
    }
#pragma unroll
    for (int mq = 0; mq < 2; mq++)
#pragma unroll
        for (int r = 0; r < 4; r++) {
            float s = lsum[mq][r];
            s += __shfl_xor(s, 1); s += __shfl_xor(s, 2);
            s += __shfl_xor(s, 4); s += __shfl_xor(s, 8);
            if (lr == 0)
                sums4[((size_t)bh * QT_ + q0 + mq * 16 + lg * 4 + r) * 4 + ns] = s;
        }
}

// -------------------- attn pass B: write attn + partial PV (8 waves x 32 q-rows) ----------
__global__ __launch_bounds__(512, 4) void attn_pv(const u16* __restrict__ qh,
                                                  const u16* __restrict__ kh,
                                                  const u16* __restrict__ vt,
                                                  const int* __restrict__ kv_mask,
                                                  const float* __restrict__ sums4,
                                                  float* __restrict__ attn_out,
                                                  float* __restrict__ pvpart) {
    __shared__ __align__(16) u16 kbuf[2][64 * 64];
    __shared__ __align__(16) u16 vbuf[2][64 * 64];
    __shared__ unsigned PW[8][32][32];  // per-wave packed bf16-pair P (32 q), granule-swz

    const int id = blockIdx.x;
    const int sw = (id & 7) * 64 + (id >> 3);   // XCD k gets 4 consecutive bh
    const int bh = sw >> 4, qt = (sw >> 2) & 3, ns = sw & 3;
    const int b = bh >> 3;
    const int tid = threadIdx.x, w = tid >> 6, lane = tid & 63;
    const int lr = lane & 15, lg = lane >> 4;
    const int q0 = qt * 256 + w * 32;

    const u16* qbase = qh + (bh * QT_ + q0) * DH_;
    bf16x8 qf[2][2];
#pragma unroll
    for (int mq = 0; mq < 2; mq++) {
        qf[mq][0] = ldbf8(qbase + (mq * 16 + lr) * DH_ + lg * 8);       // Q pre-scaled
        qf[mq][1] = ldbf8(qbase + (mq * 16 + lr) * DH_ + 32 + lg * 8);
    }
    const u16* kbase = kh + (size_t)bh * (N_ * DH_) + ns * 512 * DH_;
    const u16* vbase = vt + (size_t)bh * (N_ * DH_) + ns * 512 * DH_;  // [8 t][64 d][64]
    const int* mbase = kv_mask + b * N_ + ns * 512;

    // total row sums -> inv
    float inv[2][4];
#pragma unroll
    for (int mq = 0; mq < 2; mq++)
#pragma unroll
        for (int r = 0; r < 4; r++) {
            float4 s4 = *reinterpret_cast<const float4*>(
                sums4 + ((size_t)bh * QT_ + q0 + mq * 16 + lg * 4 + r) * 4);
            float tot = s4.x + s4.y + s4.z + s4.w;
            inv[mq][r] = (tot > 0.f) ? (1.0f / tot) : 0.f;  // all-masked -> attn = ctx = 0
        }

    // stage K tile [64 kv][64 d] + V tile [64 d][64 kv]: wave w stages rows [w*8, w*8+8)
    auto stage = [&](int t, u16* kb, u16* vb) {
        const int r0 = w * 8;
        const int row = r0 + (lane >> 3);
        const int gsw = ((lane & 7) ^ (row & 7)) * 8;
        g2lds16(kbase + (t * 64 + row) * 64 + gsw, kb + r0 * 64);
        g2lds16(vbase + (t * 64 + row) * 64 + gsw, vb + r0 * 64);
    };

    f32x4 pv[2][4];
#pragma unroll
    for (int mq = 0; mq < 2; mq++)
#pragma unroll
        for (int i = 0; i < 4; i++) pv[mq][i] = f32x4{0.f, 0.f, 0.f, 0.f};
    unsigned(*P)[32] = PW[w];
    float* abase = attn_out + ((size_t)(bh * QT_ + q0)) * N_ + ns * 512;
    const int srow = lane >> 4, cq = lane & 15;  // store: 4 rows x 256B per instr

    stage(0, kbuf[0], vbuf[0]);
    __syncthreads();
    for (int t = 0; t < 8; t++) {
        const u16* kc = kbuf[t & 1];
        const u16* vc = vbuf[t & 1];
        if (t < 7) stage(t + 1, kbuf[(t + 1) & 1], vbuf[(t + 1) & 1]);
#pragma unroll
        for (int n = 0; n < 4; n++) {
            const int krow = n * 16 + lr;
            const u16* kp = kc + krow * 64;
            bf16x8 k0 = ldbf8(kp + ((lg ^ (krow & 7)) * 8));
            bf16x8 k1 = ldbf8(kp + (((lg + 4) ^ (krow & 7)) * 8));
            f32x4 c0 = f32x4{0.f, 0.f, 0.f, 0.f};
            f32x4 c1 = f32x4{0.f, 0.f, 0.f, 0.f};
            __builtin_amdgcn_s_setprio(1);
            c0 = MFMA16(qf[0][0], k0, c0);
            c0 = MFMA16(qf[0][1], k1, c0);
            c1 = MFMA16(qf[1][0], k0, c1);
            c1 = MFMA16(qf[1][1], k1, c1);
            __builtin_amdgcn_s_setprio(0);
            const bool keep = (mbase[t * 64 + krow] != 0);
#pragma unroll
            for (int mq = 0; mq < 2; mq++) {
#pragma unroll
                for (int r = 0; r < 4; r++) {
                    float p = keep ? (__expf((mq ? c1 : c0)[r]) * inv[mq][r]) : 0.f;
                    float hi = __shfl_xor(p, 1);
                    __bf16 lo_b = (__bf16)p, hi_b = (__bf16)hi;
                    unsigned pk = ((unsigned)__builtin_bit_cast(u16, hi_b) << 16) |
                                  (unsigned)__builtin_bit_cast(u16, lo_b);
                    if (!(lr & 1)) {
                        const int row = mq * 16 + lg * 4 + r, c32 = n * 8 + (lr >> 1);
                        P[row][(((c32 >> 2) ^ (row & 7)) << 2) + (c32 & 3)] = pk;
                    }
                }
            }
        }
        // attn stores: read packed P (b64), unpack bf16->f32, 4 rows x 256B segments
#pragma unroll
        for (int i = 0; i < 8; i++) {
            const int row = i * 4 + srow, rw = row & 7;
            const int m = (((cq >> 1) ^ rw) << 2) + ((cq & 1) << 1);
            uint2 pp = *reinterpret_cast<const uint2*>(&P[row][m]);
            f32x4 vv;
            vv[0] = __builtin_bit_cast(float, pp.x << 16);
            vv[1] = __builtin_bit_cast(float, pp.x & 0xffff0000u);
            vv[2] = __builtin_bit_cast(float, pp.y << 16);
            vv[3] = __builtin_bit_cast(float, pp.y & 0xffff0000u);
            *reinterpret_cast<f32x4*>(abase + (size_t)row * N_ + t * 64 + cq * 4) = vv;
        }
        // PV: ctx[32q,64d] += P @ V-tile; V b128 frags loaded once, reused for both mq
#pragma unroll
        for (int ks = 0; ks < 2; ks++) {
            bf16x8 bv[4];
#pragma unroll
            for (int nb = 0; nb < 4; nb++) {
                const int vrow = nb * 16 + lr;
                bv[nb] = ldbf8(vc + vrow * 64 + (((ks * 4 + lg) ^ (vrow & 7)) * 8));
            }
            const int g = (4 * ks + lg) ^ (lr & 7);
#pragma unroll
            for (int mq = 0; mq < 2; mq++) {
                uint4 a4 = *reinterpret_cast<const uint4*>(&P[mq * 16 + lr][g << 2]);
                bf16x8 af = __builtin_bit_cast(bf16x8, a4);
                __builtin_amdgcn_s_setprio(1);
#pragma unroll
                for (int nb = 0; nb < 4; nb++)
                    pv[mq][nb] = MFMA16(af, bv[nb], pv[mq][nb]);
                __builtin_amdgcn_s_setprio(0);
            }
        }
        __syncthreads();
    }

    // partial ctx: pvpart[ns][bh][q][64]
    float* pbase = pvpart + (((size_t)ns * 32 + bh) * QT_) * DH_;
#pragma unroll
    for (int mq = 0; mq < 2; mq++)
#pragma unroll
        for (int nb = 0; nb < 4; nb++)
#pragma unroll
            for (int r = 0; r < 4; r++)
                pbase[(size_t)(q0 + mq * 16 + lg * 4 + r) * DH_ + nb * 16 + lr] = pv[mq][nb][r];
}

// -------------------- ctx reduce: ctx[b,tok,h*64+d] = bf16(sum_ns pvpart) ------------
__global__ __launch_bounds__(256) void ctx_reduce(const float* __restrict__ pvpart,
                                                  u16* __restrict__ ctx) {
    const size_t SL = (size_t)32 * QT_ * DH_;  // slice stride (f32)
    const int i = blockIdx.x * 256 + threadIdx.x;  // 524288 threads, 4 elems each
    const int base = i * 4;
    const int d = base & 63, h = (base >> 6) & 7;
    const int bt = base >> 9;              // b*1024 + tok
    const size_t pi = (((size_t)(bt >> 10) * 8 + h) * QT_ + (bt & 1023)) * DH_ + d;
    f32x4 s0 = *reinterpret_cast<const f32x4*>(pvpart + pi);
    f32x4 s1 = *reinterpret_cast<const f32x4*>(pvpart + SL + pi);
    f32x4 s2 = *reinterpret_cast<const f32x4*>(pvpart + 2 * SL + pi);
    f32x4 s3 = *reinterpret_cast<const f32x4*>(pvpart + 3 * SL + pi);
    u16x4 o;
#pragma unroll
    for (int j = 0; j < 4; j++) o[j] = f2bf((s0[j] + s1[j]) + (s2[j] + s3[j]));
    *reinterpret_cast<u16x4*>(ctx + base) = o;
}

// -------------------- O projection: 64x64 tiles, grid 512 --------------------
__global__ __launch_bounds__(256) void proj_o(const u16* __restrict__ X,
                                              const u16* __restrict__ Wt,
                                              const float* __restrict__ bias,
                                              float* __restrict__ outp,
                                              const int* __restrict__ qmask) {
    __shared__ __align__(16) u16 la[2][64 * 64];
    __shared__ __align__(16) u16 lb[2][64 * 64];

    const int id = blockIdx.x;             // 512 blocks
    const int sw = (id & 7) * 64 + (id >> 3);
    const int m0 = (sw >> 3) * 64, n0 = (sw & 7) * 64;

    const int tid = threadIdx.x, w = tid >> 6, lane = tid & 63;
    const int lr = lane & 15, lg = lane >> 4;
    const int wml = (w >> 1) * 32, wnl = (w & 1) * 32;

    auto stage = [&](const u16* gsrc, u16* lbuf) {
#pragma unroll
        for (int i = 0; i < 2; i++) {
            const int r0 = w * 16 + i * 8;
            const int row = r0 + (lane >> 3);
            const u16* src = gsrc + row * E_ + (((lane & 7) ^ (row & 7)) * 8);
            g2lds16(src, lbuf + r0 * 64);
        }
    };

    f32x4 acc[2][2];
#pragma unroll
    for (int i = 0; i < 2; i++)
#pragma unroll
        for (int j = 0; j < 2; j++) acc[i][j] = f32x4{0.f, 0.f, 0.f, 0.f};

    stage(X + m0 * E_, la[0]);
    stage(Wt + n0 * E_, lb[0]);
    __syncthreads();
    int buf = 0;
    for (int kt = 0; kt < E_ / 64; kt++) {
        if (kt + 1 < E_ / 64) {
            stage(X + m0 * E_ + (kt + 1) * 64, la[buf ^ 1]);
            stage(Wt + n0 * E_ + (kt + 1) * 64, lb[buf ^ 1]);
        }
#pragma unroll
        for (int ks = 0; ks < 2; ks++) {
            bf16x8 a[2], bb[2];
#pragma unroll
            for (int mb = 0; mb < 2; mb++) {
                const int r = wml + mb * 16 + lr;
                a[mb] = ldbf8(la[buf] + r * 64 + (((ks * 4 + lg) ^ (r & 7)) * 8));
            }
#pragma unroll
            for (int nb = 0; nb < 2; nb++) {
                const int r = wnl + nb * 16 + lr;
                bb[nb] = ldbf8(lb[buf] + r * 64 + (((ks * 4 + lg) ^ (r & 7)) * 8));
            }
            __builtin_amdgcn_s_setprio(1);
#pragma unroll
            for (int mb = 0; mb < 2; mb++)
#pragma unroll
                for (int nb = 0; nb < 2; nb++)
                    acc[mb][nb] = MFMA16(a[mb], bb[nb], acc[mb][nb]);
            __builtin_amdgcn_s_setprio(0);
        }
        __syncthreads();
        buf ^= 1;
    }

#pragma unroll
    for (int mb = 0; mb < 2; mb++) {
#pragma unroll
        for (int nb = 0; nb < 2; nb++) {
            const int col = n0 + wnl + nb * 16 + lr;
            const float bs = bias[col];
#pragma unroll
            for (int r = 0; r < 4; r++) {
                const int row = m0 + wml + mb * 16 + lg * 4 + r;
                float v = acc[mb][nb][r] + bs;
                float m = (qmask[row] != 0) ? 1.0f : 0.0f;
                outp[row * E_ + col] = v * m;
            }
        }
    }
}

// -------------------- host launch --------------------
extern "C" void kernel_launch(void* const* d_in, const int* in_sizes, int n_in,
                              void* d_out, int out_size, void* d_ws, size_t ws_size,
                              hipStream_t stream) {
    (void)in_sizes; (void)n_in; (void)out_size; (void)ws_size;
    const float* q   = (const float*)d_in[0];
    const float* kv  = (const float*)d_in[1];
    const int* q_mask  = (const int*)d_in[2];
    const int* kv_mask = (const int*)d_in[3];
    const int* q_pos   = (const int*)d_in[4];
    const int* kv_pos  = (const int*)d_in[5];
    const float* Wq = (const float*)d_in[6];  const float* bq = (const float*)d_in[7];
    const float* Wk = (const float*)d_in[8];  const float* bk = (const float*)d_in[9];
    const float* Wv = (const float*)d_in[10]; const float* bv = (const float*)d_in[11];
    const float* Wo = (const float*)d_in[12]; const float* bo = (const float*)d_in[13];
    float* outp = (float*)d_out;

    char* ws = (char*)d_ws;
    size_t off = 0;
    auto carve = [&](size_t bytes) -> void* {
        void* p = ws + off;
        off = (off + bytes + 255) & ~(size_t)255;
        return p;
    };
    u16* qbf    = (u16*)carve((size_t)B_ * QT_ * E_ * 2);
    u16* kvbf   = (u16*)carve((size_t)B_ * N_ * E_ * 2);
    u16* wt4    = (u16*)carve((size_t)4 * E_ * E_ * 2);  // [Wq^T|Wk^T|Wv^T|Wo^T]
    u16* qhh    = (u16*)carve((size_t)B_ * H_ * QT_ * DH_ * 2);
    u16* khh    = (u16*)carve((size_t)B_ * H_ * N_ * DH_ * 2);
    u16* vt     = (u16*)carve((size_t)B_ * H_ * DH_ * N_ * 2);  // tiled [bh][32][64][64]
    u16* ctx    = (u16*)carve((size_t)B_ * QT_ * E_ * 2);
    float2* tq  = (float2*)carve((size_t)B_ * QT_ * 16 * sizeof(float2));
    float2* tk  = (float2*)carve((size_t)B_ * N_ * 16 * sizeof(float2));
    float* sums4  = (float*)carve((size_t)B_ * H_ * QT_ * 4 * sizeof(float));
    float* pvpart = (float*)carve((size_t)4 * B_ * H_ * QT_ * DH_ * sizeof(float));

    prep_all<<<7168, 256, 0, stream>>>(q, kv, Wq, Wk, Wv, Wo, q_pos, kv_pos,
                                       qbf, kvbf, wt4, tq, tk);

    proj_qkv<<<640, 256, 0, stream>>>(qbf, kvbf, wt4, bq, bk, bv, qhh, khh, vt, tq, tk);

    attn_sums<<<512, 512, 0, stream>>>(qhh, khh, kv_mask, sums4);
    attn_pv<<<512, 512, 0, stream>>>(qhh, khh, vt, kv_mask, sums4,
                                     outp + (size_t)B_ * QT_ * E_, pvpart);
    ctx_reduce<<<2048, 256, 0, stream>>>(pvpart, ctx);

    proj_o<<<512, 256, 0, stream>>>(ctx, wt4 + 3 * 512 * 512, bo, outp, q_mask);
}